// Round 1
// baseline (24.337 us; speedup 1.0000x reference)
//
#include <hip/hip_runtime.h>
#include <cfloat>

#define TPB 64          // TOKENS_PER_BLOCK
#define SCPB 4          // SUB_CHUNK_PER_BLOCK
#define TPSC 16         // TOKENS_PER_SUB_CHUNK

__global__ __launch_bounds__(256) void paged_minmax_kernel(
    const float* __restrict__ keys,
    const int* __restrict__ block_tables,
    const int* __restrict__ cu_seqlens,
    const int* __restrict__ heads_idx,
    float* __restrict__ out,
    int B, int MB, int H, int D, int Hp)
{
    const int n_chunks = MB * SCPB;
    const int bc = blockIdx.x;
    const int b = bc / n_chunks;
    const int c = bc - b * n_chunks;

    const int len = cu_seqlens[b + 1] - cu_seqlens[b];
    int nv = len - c * TPSC;
    if (nv > TPSC) nv = TPSC;

    const int tid = threadIdx.x;            // 0..Hp*D/4-1
    const int d4_per_head = D >> 2;          // 32 for D=128
    const int h = tid / d4_per_head;
    const int d4 = tid - h * d4_per_head;

    const size_t s_stride = (size_t)B * n_chunks * Hp * D;   // min->max offset
    float* out_min = out + ((size_t)b * n_chunks + c) * (size_t)(Hp * D) + (size_t)tid * 4;
    float* out_max = out_min + s_stride;

    if (nv <= 0) {
        float4 z = make_float4(0.f, 0.f, 0.f, 0.f);
        *reinterpret_cast<float4*>(out_min) = z;
        *reinterpret_cast<float4*>(out_max) = z;
        return;
    }

    const int blk = block_tables[b * MB + (c >> 2)];
    const int t0 = (c & (SCPB - 1)) * TPSC;
    const int hp = heads_idx[h];

    const float4* src = reinterpret_cast<const float4*>(
        keys + ((size_t)blk * TPB + t0) * (size_t)(H * D) + (size_t)hp * D) + d4;
    const int tstride = (H * D) >> 2;        // float4 units between tokens

    float4 v0 = src[0];
    float4 vmin = v0, vmax = v0;

    if (nv == TPSC) {
        // common case: fully unrolled, 15 more independent loads
        #pragma unroll
        for (int t = 1; t < TPSC; ++t) {
            float4 x = src[(size_t)t * tstride];
            vmin.x = fminf(vmin.x, x.x); vmax.x = fmaxf(vmax.x, x.x);
            vmin.y = fminf(vmin.y, x.y); vmax.y = fmaxf(vmax.y, x.y);
            vmin.z = fminf(vmin.z, x.z); vmax.z = fmaxf(vmax.z, x.z);
            vmin.w = fminf(vmin.w, x.w); vmax.w = fmaxf(vmax.w, x.w);
        }
    } else {
        for (int t = 1; t < nv; ++t) {
            float4 x = src[(size_t)t * tstride];
            vmin.x = fminf(vmin.x, x.x); vmax.x = fmaxf(vmax.x, x.x);
            vmin.y = fminf(vmin.y, x.y); vmax.y = fmaxf(vmax.y, x.y);
            vmin.z = fminf(vmin.z, x.z); vmax.z = fmaxf(vmax.z, x.z);
            vmin.w = fminf(vmin.w, x.w); vmax.w = fmaxf(vmax.w, x.w);
        }
    }

    *reinterpret_cast<float4*>(out_min) = vmin;
    *reinterpret_cast<float4*>(out_max) = vmax;
}

extern "C" void kernel_launch(void* const* d_in, const int* in_sizes, int n_in,
                              void* d_out, int out_size, void* d_ws, size_t ws_size,
                              hipStream_t stream) {
    const float* keys        = (const float*)d_in[0];
    const int*   block_tables= (const int*)d_in[1];
    const int*   cu_seqlens  = (const int*)d_in[2];
    const int*   heads_idx   = (const int*)d_in[3];
    float* out = (float*)d_out;

    const int B  = in_sizes[2] - 1;                 // 4
    const int MB = in_sizes[1] / B;                 // 128
    const int Hp = in_sizes[3];                     // 8
    const int D  = 128;
    const long long num_blocks_tokens = (long long)in_sizes[1] * TPB; // B*MB*64
    const int H  = (int)((long long)in_sizes[0] / num_blocks_tokens / D); // 8

    const int n_chunks = MB * SCPB;
    const int grid = B * n_chunks;                  // 2048
    const int threads = (Hp * D) / 4;               // 256

    paged_minmax_kernel<<<grid, threads, 0, stream>>>(
        keys, block_tables, cu_seqlens, heads_idx, out, B, MB, H, D, Hp);
}